// Round 8
// baseline (2116.227 us; speedup 1.0000x reference)
//
#include <hip/hip_runtime.h>
#include <math.h>

// ---------------- problem constants ----------------
#define BB     32
#define NN     64
#define DIMM   512
#define HEADS  4
#define DH     128
#define FFD    2048
#define JJ     2048
#define RX     2048
#define TOPKK  64
#define CH     8192
#define NCH    8
#define FLTMAXF 3.402823466e38f

// workspace words (4B) required (331.4 MB; ws >= 356.5 MB proven in R4/R5)
#define WS_WORDS_REQ 82837504ull

typedef unsigned short u16;
typedef unsigned int   u32;

using f32x4  = __attribute__((ext_vector_type(4))) float;
using short8 = __attribute__((ext_vector_type(8))) short;   // 8 bf16 (4 VGPRs)

__device__ __forceinline__ float wred_sum(float v) {
    #pragma unroll
    for (int m = 1; m < 64; m <<= 1) v += __shfl_xor(v, m, 64);
    return v;
}
__device__ __forceinline__ int wred_sumi(int v) {
    #pragma unroll
    for (int m = 1; m < 64; m <<= 1) v += __shfl_xor(v, m, 64);
    return v;
}
__device__ __forceinline__ float wred_max(float v) {
    #pragma unroll
    for (int m = 1; m < 64; m <<= 1) v = fmaxf(v, __shfl_xor(v, m, 64));
    return v;
}
__device__ __forceinline__ unsigned fkey(float f) {
    unsigned u = __float_as_uint(f);
    return (u & 0x80000000u) ? ~u : (u | 0x80000000u);
}

// bf16 helpers (RNE)
__device__ __forceinline__ u16 bf16rne(float f) {
    u32 u = __float_as_uint(f);
    return (u16)((u + 0x7FFFu + ((u >> 16) & 1u)) >> 16);
}
__device__ __forceinline__ float bf16tof(u16 h) {
    return __uint_as_float(((u32)h) << 16);
}
__device__ __forceinline__ void split2(float f, u16& h, u16& l) {
    h = bf16rne(f);
    l = bf16rne(f - bf16tof(h));
}

// async global->LDS, 16B/lane; LDS dest wave-uniform base, global src per-lane.
__device__ __forceinline__ void gload16(const void* g, void* l) {
    __builtin_amdgcn_global_load_lds(
        (const __attribute__((address_space(1))) void*)g,
        (__attribute__((address_space(3))) void*)l,
        16, 0, 0);
}

// ---------------- LayerNorm (f32 out) ----------------
__global__ __launch_bounds__(256) void ln_k(const float* __restrict__ in,
                                            const float* __restrict__ gam,
                                            const float* __restrict__ bet,
                                            float* __restrict__ out)
{
    const int row  = blockIdx.x * 4 + (threadIdx.x >> 6);
    const int lane = threadIdx.x & 63;
    const float* p = in + (size_t)row * DIMM + lane * 8;

    float a[8];
    *(float4*)&a[0] = *(const float4*)p;
    *(float4*)&a[4] = *(const float4*)(p + 4);

    float s = 0.f;
    #pragma unroll
    for (int i = 0; i < 8; ++i) s += a[i];
    s = wred_sum(s);
    const float mean = s * (1.0f / DIMM);

    float vs = 0.f;
    #pragma unroll
    for (int i = 0; i < 8; ++i) { float d = a[i] - mean; vs += d * d; }
    vs = wred_sum(vs);
    const float var = vs * (1.0f / DIMM) + 1e-5f;
    float r = rsqrtf(var);
    r = r * (1.5f - 0.5f * var * r * r);

    float g[8], b[8];
    *(float4*)&g[0] = *(const float4*)(gam + lane * 8);
    *(float4*)&g[4] = *(const float4*)(gam + lane * 8 + 4);
    *(float4*)&b[0] = *(const float4*)(bet + lane * 8);
    *(float4*)&b[4] = *(const float4*)(bet + lane * 8 + 4);

    float o[8];
    #pragma unroll
    for (int i = 0; i < 8; ++i) o[i] = g[i] * (a[i] - mean) * r + b[i];

    float* q = out + (size_t)row * DIMM + lane * 8;
    *(float4*)q       = *(float4*)&o[0];
    *(float4*)(q + 4) = *(float4*)&o[4];
}

// ---------------- LayerNorm -> split bf16 (hi,lo) ----------------
__global__ __launch_bounds__(256) void ln_split_k(const float* __restrict__ in,
                                                  const float* __restrict__ gam,
                                                  const float* __restrict__ bet,
                                                  u16* __restrict__ oh,
                                                  u16* __restrict__ ol)
{
    const int row  = blockIdx.x * 4 + (threadIdx.x >> 6);
    const int lane = threadIdx.x & 63;
    const float* p = in + (size_t)row * DIMM + lane * 8;

    float a[8];
    *(float4*)&a[0] = *(const float4*)p;
    *(float4*)&a[4] = *(const float4*)(p + 4);

    float s = 0.f;
    #pragma unroll
    for (int i = 0; i < 8; ++i) s += a[i];
    s = wred_sum(s);
    const float mean = s * (1.0f / DIMM);

    float vs = 0.f;
    #pragma unroll
    for (int i = 0; i < 8; ++i) { float d = a[i] - mean; vs += d * d; }
    vs = wred_sum(vs);
    const float var = vs * (1.0f / DIMM) + 1e-5f;
    float r = rsqrtf(var);
    r = r * (1.5f - 0.5f * var * r * r);

    float g[8], b[8];
    *(float4*)&g[0] = *(const float4*)(gam + lane * 8);
    *(float4*)&g[4] = *(const float4*)(gam + lane * 8 + 4);
    *(float4*)&b[0] = *(const float4*)(bet + lane * 8);
    *(float4*)&b[4] = *(const float4*)(bet + lane * 8 + 4);

    u32 ph[4], pl[4];
    #pragma unroll
    for (int i = 0; i < 4; ++i) {
        float o0 = g[2*i]   * (a[2*i]   - mean) * r + b[2*i];
        float o1 = g[2*i+1] * (a[2*i+1] - mean) * r + b[2*i+1];
        u16 h0, l0, h1, l1;
        split2(o0, h0, l0);
        split2(o1, h1, l1);
        ph[i] = (u32)h0 | ((u32)h1 << 16);
        pl[i] = (u32)l0 | ((u32)l1 << 16);
    }
    uint4 vh; vh.x = ph[0]; vh.y = ph[1]; vh.z = ph[2]; vh.w = ph[3];
    uint4 vl; vl.x = pl[0]; vl.y = pl[1]; vl.z = pl[2]; vl.w = pl[3];
    *(uint4*)(oh + (size_t)row * DIMM + lane * 8) = vh;
    *(uint4*)(ol + (size_t)row * DIMM + lane * 8) = vl;
}

// ---------------- weight transpose + split ----------------
__global__ __launch_bounds__(256) void wsplit_k(const float* __restrict__ W,
                                                u16* __restrict__ Th, u16* __restrict__ Tl,
                                                int K, int N)
{
    __shared__ float t[64][65];
    const int k0 = blockIdx.y * 64, n0 = blockIdx.x * 64;
    const int tid = threadIdx.x;
    #pragma unroll
    for (int p = 0; p < 16; ++p) {
        const int idx = p * 256 + tid;
        const int r = idx >> 6, c = idx & 63;
        t[r][c] = W[(size_t)(k0 + r) * N + n0 + c];
    }
    __syncthreads();
    #pragma unroll
    for (int p = 0; p < 16; ++p) {
        const int idx = p * 256 + tid;
        const int r = idx >> 6, c = idx & 63;
        float v = t[c][r];
        u16 h, l; split2(v, h, l);
        Th[(size_t)(n0 + r) * K + k0 + c] = h;
        Tl[(size_t)(n0 + r) * K + k0 + c] = l;
    }
}

// ---------------- split-bf16 MFMA GEMM: double-buffered 2-phase pipeline (T3 minimum) ----------
// C = A[M,K] @ B^T[N,K]^T, 3-term: ahi*bhi + ahi*blo + alo*bhi.
// 128x128 tile, BK=32, 4 waves 2x2, 4x4 frags of 16x16x32. XCD-chunk swizzle (T1).
// Schedule per K-step (catalog T3 "minimum 2-phase"):
//   STAGE(buf^1, t+1)  ->  ds_read+MFMA on buf  ->  __syncthreads (vmcnt0 drain + barrier)
// Staging latency hides under the MFMA phase; the drain at step end finds loads complete.
// sched_barrier(0) pins the stage-issue before the ds_reads (compiler could alias-prove
// the buffers disjoint and sink the loads, destroying overlap).
// Hazards: buf written at t+1 was read at t (reads land in regs pre-barrier) -> safe.
#define SM_SWISH          0
#define SM_RESHALF_F32    1
#define SM_RESHALF_SPLIT  2
#define SM_Q              3
#define SM_KV             4
#define SM_RESBIAS        5

template<int MODE>
__global__ __launch_bounds__(256, 2) void mgemm_k(
    const u16* __restrict__ Ahi, const u16* __restrict__ Alo,
    const u16* __restrict__ Bhi, const u16* __restrict__ Blo,
    const float* __restrict__ bias, const float* __restrict__ res,
    float* __restrict__ o1, u16* __restrict__ o2, u16* __restrict__ o3,
    u16* __restrict__ o4, int N, int K, int row0)
{
    __shared__ u16 sAh[2][128 * 32], sAl[2][128 * 32], sBh[2][128 * 32], sBl[2][128 * 32];

    const int tid  = threadIdx.x;
    // bijective XCD-chunk swizzle (nwg multiple of 8)
    const int nwg  = gridDim.x * gridDim.y;
    int bid = blockIdx.y * gridDim.x + blockIdx.x;
    bid = (bid & 7) * (nwg >> 3) + (bid >> 3);
    const int bm   = (bid / gridDim.x) * 128;
    const int bn   = (bid % gridDim.x) * 128;

    const int lane = tid & 63;
    const int wid  = tid >> 6;
    const int wr   = (wid >> 1) * 64;
    const int wc   = (wid & 1) * 64;
    const int colL = lane & 15;
    const int rowL = (lane >> 4) * 4;
    const int kL   = (lane >> 4) * 8;
    const int srow = lane >> 2;
    const int skc  = (lane & 3) * 8;

    const f32x4 z4 = {0.f, 0.f, 0.f, 0.f};
    f32x4 acc[4][4];
    #pragma unroll
    for (int i = 0; i < 4; ++i)
        #pragma unroll
        for (int j = 0; j < 4; ++j) acc[i][j] = z4;

    // staging: 8 async loads/wave into buffer `bf` for K-offset k0
    #define STAGE_TILE(bf, k0)                                                    \
        {                                                                         \
            _Pragma("unroll")                                                     \
            for (int ss = 0; ss < 2; ++ss) {                                      \
                const int s = wid * 2 + ss;                                       \
                const int r = s * 16 + srow;                                      \
                const size_t ga = (size_t)(bm + r) * K + (k0) + skc;              \
                const size_t gb = (size_t)(bn + r) * K + (k0) + skc;              \
                gload16(&Ahi[ga], &sAh[bf][s * 512]);                             \
                gload16(&Alo[ga], &sAl[bf][s * 512]);                             \
                gload16(&Bhi[gb], &sBh[bf][s * 512]);                             \
                gload16(&Blo[gb], &sBl[bf][s * 512]);                             \
            }                                                                     \
        }

    const int nt = K >> 5;
    STAGE_TILE(0, 0);
    __syncthreads();                       // prologue drain

    int cur = 0;
    for (int t = 0; t < nt; ++t) {
        if (t + 1 < nt) STAGE_TILE(cur ^ 1, (t + 1) << 5);
        __builtin_amdgcn_sched_barrier(0); // pin: issue loads before ds_reads/MFMA

        short8 ah[4], al[4], bh[4], bl[4];
        #pragma unroll
        for (int f = 0; f < 4; ++f) {
            const int ra = (wr + f * 16 + colL) * 32 + kL;
            ah[f] = *(const short8*)&sAh[cur][ra];
            al[f] = *(const short8*)&sAl[cur][ra];
            const int rb = (wc + f * 16 + colL) * 32 + kL;
            bh[f] = *(const short8*)&sBh[cur][rb];
            bl[f] = *(const short8*)&sBl[cur][rb];
        }
        #pragma unroll
        for (int fm = 0; fm < 4; ++fm)
            #pragma unroll
            for (int fn = 0; fn < 4; ++fn) {
                acc[fm][fn] = __builtin_amdgcn_mfma_f32_16x16x32_bf16(ah[fm], bh[fn], acc[fm][fn], 0, 0, 0);
                acc[fm][fn] = __builtin_amdgcn_mfma_f32_16x16x32_bf16(ah[fm], bl[fn], acc[fm][fn], 0, 0, 0);
                acc[fm][fn] = __builtin_amdgcn_mfma_f32_16x16x32_bf16(al[fm], bh[fn], acc[fm][fn], 0, 0, 0);
            }

        cur ^= 1;
        if (t + 1 < nt) __syncthreads();   // drain staging (overlapped w/ MFMA) + barrier
    }
    #undef STAGE_TILE

    float biasc[4];
    #pragma unroll
    for (int fn = 0; fn < 4; ++fn) biasc[fn] = bias[bn + wc + fn * 16 + colL];

    #pragma unroll
    for (int fm = 0; fm < 4; ++fm) {
        #pragma unroll
        for (int fn = 0; fn < 4; ++fn) {
            const int gc = bn + wc + fn * 16 + colL;
            #pragma unroll
            for (int r = 0; r < 4; ++r) {
                const int gr = bm + wr + fm * 16 + rowL + r;
                float o = acc[fm][fn][r] + biasc[fn];
                if (MODE == SM_SWISH) {
                    float s = o / (1.f + expf(-o));
                    u16 h, l; split2(s, h, l);
                    o2[(size_t)gr * N + gc] = h;
                    o3[(size_t)gr * N + gc] = l;
                } else if (MODE == SM_RESHALF_F32) {
                    o1[(size_t)gr * N + gc] = res[(size_t)gr * N + gc] + 0.5f * o;
                } else if (MODE == SM_RESHALF_SPLIT) {
                    float v = res[(size_t)gr * N + gc] + 0.5f * o;
                    u16 h, l; split2(v, h, l);
                    o2[(size_t)gr * N + gc] = h;
                    o3[(size_t)gr * N + gc] = l;
                } else if (MODE == SM_Q) {
                    const int b_ = gr >> 6, i_ = gr & 63, h_ = gc >> 7, d_ = gc & 127;
                    const size_t idx = (((size_t)(b_ * HEADS + h_) * NN + i_) << 7) + d_;
                    u16 h, l; split2(o, h, l);
                    o2[idx] = h; o3[idx] = l;
                } else if (MODE == SM_KV) {
                    const int grow = row0 + gr;
                    const int b_ = grow >> 11, j_ = grow & 2047;
                    if (gc < DIMM) {
                        const int h_ = gc >> 7, d_ = gc & 127;
                        const size_t idx = (((size_t)(b_ * HEADS + h_) * JJ + j_) << 7) + d_;
                        u16 h, l; split2(o, h, l);
                        o2[idx] = h; o3[idx] = l;
                    } else {
                        const int cc2 = gc - DIMM;
                        const int h_ = cc2 >> 7, d_ = cc2 & 127;
                        o4[((size_t)(b_ * HEADS + h_) * DH + d_) * JJ + j_] = bf16rne(o);
                    }
                } else {  // SM_RESBIAS
                    o1[(size_t)gr * N + gc] = res[(size_t)gr * N + gc] + o;
                }
            }
        }
    }
}

// ---------------- dots = scale * Q @ K^T (3-term split MFMA) ----------------
__global__ __launch_bounds__(256, 2) void dmfma_k(
    const u16* __restrict__ Qh, const u16* __restrict__ Ql,
    const u16* __restrict__ Kh, const u16* __restrict__ Kl,
    float* __restrict__ dots)
{
    __shared__ u16 sQh[64 * 32], sQl[64 * 32], sKh[128 * 32], sKl[128 * 32];

    const int tid  = threadIdx.x;
    const int bh   = blockIdx.y;
    const int jt   = blockIdx.x * 128;
    const int lane = tid & 63;
    const int wid  = tid >> 6;
    const int wr   = (wid >> 1) * 32;
    const int wc   = (wid & 1) * 64;
    const int colL = lane & 15;
    const int rowL = (lane >> 4) * 4;
    const int kL   = (lane >> 4) * 8;
    const int srow = lane >> 2;
    const int skc  = (lane & 3) * 8;

    const size_t qbase = (size_t)bh * NN * DH;
    const size_t kbase = (size_t)bh * JJ * DH;

    const f32x4 z4 = {0.f, 0.f, 0.f, 0.f};
    f32x4 acc[2][4];
    #pragma unroll
    for (int i = 0; i < 2; ++i)
        #pragma unroll
        for (int j = 0; j < 4; ++j) acc[i][j] = z4;

    for (int d0 = 0; d0 < DH; d0 += 32) {
        __syncthreads();
        {
            const size_t gq = qbase + (size_t)(wid * 16 + srow) * DH + d0 + skc;
            gload16(&Qh[gq], &sQh[wid * 512]);
            gload16(&Ql[gq], &sQl[wid * 512]);
        }
        #pragma unroll
        for (int ss = 0; ss < 2; ++ss) {
            const int s = wid * 2 + ss;
            const size_t gk = kbase + (size_t)(jt + s * 16 + srow) * DH + d0 + skc;
            gload16(&Kh[gk], &sKh[s * 512]);
            gload16(&Kl[gk], &sKl[s * 512]);
        }
        __syncthreads();

        short8 qh[2], ql[2], kh[4], kl[4];
        #pragma unroll
        for (int f = 0; f < 2; ++f) {
            const int ra = (wr + f * 16 + colL) * 32 + kL;
            qh[f] = *(const short8*)&sQh[ra];
            ql[f] = *(const short8*)&sQl[ra];
        }
        #pragma unroll
        for (int f = 0; f < 4; ++f) {
            const int rb = (wc + f * 16 + colL) * 32 + kL;
            kh[f] = *(const short8*)&sKh[rb];
            kl[f] = *(const short8*)&sKl[rb];
        }
        #pragma unroll
        for (int fm = 0; fm < 2; ++fm)
            #pragma unroll
            for (int fn = 0; fn < 4; ++fn) {
                acc[fm][fn] = __builtin_amdgcn_mfma_f32_16x16x32_bf16(qh[fm], kh[fn], acc[fm][fn], 0, 0, 0);
                acc[fm][fn] = __builtin_amdgcn_mfma_f32_16x16x32_bf16(qh[fm], kl[fn], acc[fm][fn], 0, 0, 0);
                acc[fm][fn] = __builtin_amdgcn_mfma_f32_16x16x32_bf16(ql[fm], kh[fn], acc[fm][fn], 0, 0, 0);
            }
    }

    const float scl = 0.08838834764831845f;
    #pragma unroll
    for (int fm = 0; fm < 2; ++fm)
        #pragma unroll
        for (int fn = 0; fn < 4; ++fn)
            #pragma unroll
            for (int r = 0; r < 4; ++r) {
                const int qi = wr + fm * 16 + rowL + r;
                const int jc = jt + wc + fn * 16 + colL;
                dots[((size_t)bh * NN + qi) * JJ + jc] = acc[fm][fn][r] * scl;
            }
}

// ---------------- top-k + masked softmax; emits P as bf16 IN-PLACE ----------------
__global__ __launch_bounds__(256) void topk_sm_k(float* __restrict__ dots)
{
    const int wid  = threadIdx.x >> 6;
    const int lane = threadIdx.x & 63;
    const int r = blockIdx.x * 4 + wid;
    const int b = r >> 8;
    const int h = (r >> 6) & 3;
    float* row = dots + (size_t)r * JJ;

    float d[32];
    unsigned key[32];
    #pragma unroll
    for (int t = 0; t < 32; ++t) {
        d[t] = row[lane + 64 * t];
        key[t] = fkey(d[t]);
    }

    unsigned cur = 0u;
    for (int bit = 31; bit >= 0; --bit) {
        const unsigned cand = cur | (1u << bit);
        int c = 0;
        #pragma unroll
        for (int t = 0; t < 32; ++t) c += (key[t] >= cand) ? 1 : 0;
        c = wred_sumi(c);
        if (c >= TOPKK) cur = cand;
    }

    const int LB = (h == 0) ? 1 : (h == 1) ? 4 : (h == 2) ? 8 : 1000;
    float m = -FLTMAXF;
    #pragma unroll
    for (int t = 0; t < 32; ++t) {
        const int j = lane + 64 * t;
        int df = (j >> 6) - b; df = (df < 0) ? -df : df;
        const bool keep = (df <= LB) && (key[t] >= cur);
        d[t] = keep ? d[t] : -FLTMAXF;
        m = fmaxf(m, d[t]);
    }
    m = wred_max(m);

    float s = 0.f;
    float e[32];
    #pragma unroll
    for (int t = 0; t < 32; ++t) {
        e[t] = expf(d[t] - m);
        s += e[t];
    }
    s = wred_sum(s);
    const float inv = 1.0f / s;

    u16* prow = (u16*)row;
    #pragma unroll
    for (int t = 0; t < 32; ++t) prow[lane + 64 * t] = bf16rne(e[t] * inv);
}

// ---------------- attn = P @ V^T-layout (bf16 MFMA, 1-term) ----------------
__global__ __launch_bounds__(256, 2) void pvm_k(
    const u16* __restrict__ Pb,     // [bh][i][j], row pitch 2*JJ u16 (in dots buffer)
    const u16* __restrict__ Vt,     // [bh][d][j]
    u16* __restrict__ attnh, u16* __restrict__ attnl)
{
    __shared__ u16 sP[64 * 32], sVt[128 * 32];

    const int tid  = threadIdx.x;
    const int bh   = blockIdx.x;
    const int lane = tid & 63;
    const int wid  = tid >> 6;
    const int wr   = (wid >> 1) * 32;
    const int wc   = (wid & 1) * 64;
    const int colL = lane & 15;
    const int rowL = (lane >> 4) * 4;
    const int kL   = (lane >> 4) * 8;
    const int srow = lane >> 2;
    const int skc  = (lane & 3) * 8;

    const size_t pbase = (size_t)bh * NN * (2 * JJ);
    const size_t vbase = (size_t)bh * DH * JJ;

    const f32x4 z4 = {0.f, 0.f, 0.f, 0.f};
    f32x4 acc[2][4];
    #pragma unroll
    for (int i = 0; i < 2; ++i)
        #pragma unroll
        for (int j = 0; j < 4; ++j) acc[i][j] = z4;

    for (int j0 = 0; j0 < JJ; j0 += 32) {
        __syncthreads();
        {
            const size_t gp = pbase + (size_t)(wid * 16 + srow) * (2 * JJ) + j0 + skc;
            gload16(&Pb[gp], &sP[wid * 512]);
        }
        #pragma unroll
        for (int ss = 0; ss < 2; ++ss) {
            const int s = wid * 2 + ss;
            const size_t gv = vbase + (size_t)(s * 16 + srow) * JJ + j0 + skc;
            gload16(&Vt[gv], &sVt[s * 512]);
        }
        __syncthreads();

        short8 pf[2], vf[4];
        #pragma unroll
        for (int f = 0; f < 2; ++f)
            pf[f] = *(const short8*)&sP[(wr + f * 16 + colL) * 32 + kL];
        #pragma unroll
        for (int f = 0; f < 4; ++f)
            vf[f] = *(const short8*)&sVt[(wc + f * 16 + colL) * 32 + kL];
        #pragma unroll
        for (int fm = 0; fm < 2; ++fm)
            #pragma unroll
            for (int fn = 0; fn < 4; ++fn)
                acc[fm][fn] = __builtin_amdgcn_mfma_f32_16x16x32_bf16(pf[fm], vf[fn], acc[fm][fn], 0, 0, 0);
    }

    const int b = bh >> 2, h = bh & 3;
    #pragma unroll
    for (int fm = 0; fm < 2; ++fm)
        #pragma unroll
        for (int fn = 0; fn < 4; ++fn)
            #pragma unroll
            for (int r = 0; r < 4; ++r) {
                const int i = wr + fm * 16 + rowL + r;
                const int dcol = wc + fn * 16 + colL;
                const size_t idx = (size_t)(b * NN + i) * DIMM + h * DH + dcol;
                u16 hh, ll; split2(acc[fm][fn][r], hh, ll);
                attnh[idx] = hh; attnl[idx] = ll;
            }
}

// ---------------- host ----------------
extern "C" void kernel_launch(void* const* d_in, const int* in_sizes, int n_in,
                              void* d_out, int out_size, void* d_ws, size_t ws_size,
                              hipStream_t stream)
{
    if (ws_size < WS_WORDS_REQ * 4ull) return;   // OOB guard

    const float* x       = (const float*)d_in[0];
    const float* ctx     = (const float*)d_in[1];
    const float* ff1_w1  = (const float*)d_in[2];
    const float* ff1_b1  = (const float*)d_in[3];
    const float* ff1_w2  = (const float*)d_in[4];
    const float* ff1_b2  = (const float*)d_in[5];
    const float* ffkv_w1 = (const float*)d_in[6];
    const float* ffkv_b1 = (const float*)d_in[7];
    const float* ffkv_w2 = (const float*)d_in[8];
    const float* ffkv_b2 = (const float*)d_in[9];
    const float* wq      = (const float*)d_in[10];
    const float* bq      = (const float*)d_in[11];
    const float* wkv     = (const float*)d_in[12];
    const float* bkv     = (const float*)d_in[13];
    const float* wo      = (const float*)d_in[14];
    const float* bo      = (const float*)d_in[15];
    const float* ln1_g   = (const float*)d_in[16];
    const float* ln1_b   = (const float*)d_in[17];
    const float* lnkv_g  = (const float*)d_in[18];
    const float* lnkv_b  = (const float*)d_in[19];
    const float* lna_g   = (const float*)d_in[20];
    const float* lna_b   = (const float*)d_in[21];
    const float* lnf_g   = (const float*)d_in[22];
    const float* lnf_b   = (const float*)d_in[23];

    float* ws = (float*)d_ws;
    // word layout (82,837,504 words = 331.4 MB) -- unchanged from R6
    u16*   Qhs = (u16*)ws;
    u16*   Qls = Qhs + 1048576;
    u16*   Khs = (u16*)(ws + 1048576);
    u16*   Kls = Khs + 33554432;
    u16*   Vt  = (u16*)(ws + 34603008);
    float* x1  = ws + 51380224;
    float* wsp = x1 + 1048576;
    float* R   = wsp + 5242880;

    u16* w1Th  = (u16*)wsp;
    u16* w1Tl  = w1Th  + 1048576;
    u16* w2Th  = w1Tl  + 1048576;
    u16* w2Tl  = w2Th  + 1048576;
    u16* kw1Th = w2Tl  + 1048576;
    u16* kw1Tl = kw1Th + 1048576;
    u16* kw2Th = kw1Tl + 1048576;
    u16* kw2Tl = kw2Th + 1048576;
    u16* wqTh  = kw2Tl + 1048576;
    u16* wqTl  = wqTh  + 262144;
    u16* wkvTh = wqTl  + 262144;
    u16* wkvTl = wkvTh + 524288;
    u16* woTh  = wkvTl + 524288;
    u16* woTl  = woTh  + 262144;

    // R overlays (temporally disjoint):
    u16* lnxh  = (u16*)R;                       // x path
    u16* lnxl  = lnxh  + 1048576;
    u16* hxh   = lnxl  + 1048576;
    u16* hxl   = hxh   + 4194304;
    u16* lnx2h = hxl   + 4194304;
    u16* lnx2l = lnx2h + 1048576;
    u16* lnch  = (u16*)R;                       // context chunks (CH=8192)
    u16* lncl  = lnch  + 4194304;
    u16* hch   = lncl  + 4194304;
    u16* hcl   = hch   + 16777216;
    u16* ctxnh = hcl   + 16777216;
    u16* ctxnl = ctxnh + 4194304;
    float* dots = R;                            // [8192][2048] f32; P bf16 in-place
    float* x2   = R;                            // after P dead
    u16* attnh  = (u16*)ws;                     // over dead Q split
    u16* attnl  = attnh + 1048576;

    // ---- weight transpose+split ----
    wsplit_k<<<dim3(FFD / 64, DIMM / 64), 256, 0, stream>>>(ff1_w1,  w1Th,  w1Tl,  DIMM, FFD);
    wsplit_k<<<dim3(DIMM / 64, FFD / 64), 256, 0, stream>>>(ff1_w2,  w2Th,  w2Tl,  FFD,  DIMM);
    wsplit_k<<<dim3(FFD / 64, DIMM / 64), 256, 0, stream>>>(ffkv_w1, kw1Th, kw1Tl, DIMM, FFD);
    wsplit_k<<<dim3(DIMM / 64, FFD / 64), 256, 0, stream>>>(ffkv_w2, kw2Th, kw2Tl, FFD,  DIMM);
    wsplit_k<<<dim3(DIMM / 64, DIMM / 64), 256, 0, stream>>>(wq,     wqTh,  wqTl,  DIMM, DIMM);
    wsplit_k<<<dim3(1024 / 64, DIMM / 64), 256, 0, stream>>>(wkv,    wkvTh, wkvTl, DIMM, 1024);
    wsplit_k<<<dim3(DIMM / 64, DIMM / 64), 256, 0, stream>>>(wo,     woTh,  woTl,  DIMM, DIMM);

    // ---- x path ----
    ln_split_k<<<RX / 4, 256, 0, stream>>>(x, ln1_g, ln1_b, lnxh, lnxl);
    mgemm_k<SM_SWISH><<<dim3(FFD / 128, RX / 128), 256, 0, stream>>>(
        lnxh, lnxl, w1Th, w1Tl, ff1_b1, nullptr, nullptr, hxh, hxl, nullptr, FFD, DIMM, 0);
    mgemm_k<SM_RESHALF_F32><<<dim3(DIMM / 128, RX / 128), 256, 0, stream>>>(
        hxh, hxl, w2Th, w2Tl, ff1_b2, x, x1, nullptr, nullptr, nullptr, DIMM, FFD, 0);
    ln_split_k<<<RX / 4, 256, 0, stream>>>(x1, lna_g, lna_b, lnx2h, lnx2l);
    mgemm_k<SM_Q><<<dim3(DIMM / 128, RX / 128), 256, 0, stream>>>(
        lnx2h, lnx2l, wqTh, wqTl, bq, nullptr, nullptr, Qhs, Qls, nullptr, DIMM, DIMM, 0);

    // ---- context chunks (CH=8192, NCH=8) ----
    for (int c = 0; c < NCH; ++c) {
        const float* cptr = ctx + (size_t)c * CH * DIMM;
        ln_split_k<<<CH / 4, 256, 0, stream>>>(cptr, lnkv_g, lnkv_b, lnch, lncl);
        mgemm_k<SM_SWISH><<<dim3(FFD / 128, CH / 128), 256, 0, stream>>>(
            lnch, lncl, kw1Th, kw1Tl, ffkv_b1, nullptr, nullptr, hch, hcl, nullptr, FFD, DIMM, 0);
        mgemm_k<SM_RESHALF_SPLIT><<<dim3(DIMM / 128, CH / 128), 256, 0, stream>>>(
            hch, hcl, kw2Th, kw2Tl, ffkv_b2, cptr, nullptr, ctxnh, ctxnl, nullptr, DIMM, FFD, 0);
        mgemm_k<SM_KV><<<dim3(1024 / 128, CH / 128), 256, 0, stream>>>(
            ctxnh, ctxnl, wkvTh, wkvTl, bkv, nullptr, nullptr, Khs, Kls, Vt, 1024, DIMM, c * CH);
    }

    // ---- attention ----
    dmfma_k<<<dim3(JJ / 128, BB * HEADS), 256, 0, stream>>>(Qhs, Qls, Khs, Kls, dots);
    topk_sm_k<<<(BB * HEADS * NN) / 4, 256, 0, stream>>>(dots);
    pvm_k<<<BB * HEADS, 256, 0, stream>>>((const u16*)dots, Vt, attnh, attnl);

    // ---- output projection + residual + final LN ----
    mgemm_k<SM_RESBIAS><<<dim3(DIMM / 128, RX / 128), 256, 0, stream>>>(
        attnh, attnl, woTh, woTl, bo, x1, x2, nullptr, nullptr, nullptr, DIMM, DIMM, 0);
    ln_k<<<RX / 4, 256, 0, stream>>>(x2, lnf_g, lnf_b, (float*)d_out);
}

// Round 10
// 1931.421 us; speedup vs baseline: 1.0957x; 1.0957x over previous
//
#include <hip/hip_runtime.h>
#include <math.h>

// ---------------- problem constants ----------------
#define BB     32
#define NN     64
#define DIMM   512
#define HEADS  4
#define DH     128
#define FFD    2048
#define JJ     2048
#define RX     2048
#define TOPKK  64
#define CH     8192
#define NCH    8
#define FLTMAXF 3.402823466e38f

// workspace words (4B) required (331.4 MB; ws >= 356.5 MB proven in R4/R5)
#define WS_WORDS_REQ 82837504ull

typedef unsigned short u16;
typedef unsigned int   u32;

using f32x4  = __attribute__((ext_vector_type(4))) float;
using short8 = __attribute__((ext_vector_type(8))) short;   // 8 bf16 (4 VGPRs)

__device__ __forceinline__ float wred_sum(float v) {
    #pragma unroll
    for (int m = 1; m < 64; m <<= 1) v += __shfl_xor(v, m, 64);
    return v;
}
__device__ __forceinline__ int wred_sumi(int v) {
    #pragma unroll
    for (int m = 1; m < 64; m <<= 1) v += __shfl_xor(v, m, 64);
    return v;
}
__device__ __forceinline__ float wred_max(float v) {
    #pragma unroll
    for (int m = 1; m < 64; m <<= 1) v = fmaxf(v, __shfl_xor(v, m, 64));
    return v;
}
__device__ __forceinline__ unsigned fkey(float f) {
    unsigned u = __float_as_uint(f);
    return (u & 0x80000000u) ? ~u : (u | 0x80000000u);
}

// bf16 helpers (RNE)
__device__ __forceinline__ u16 bf16rne(float f) {
    u32 u = __float_as_uint(f);
    return (u16)((u + 0x7FFFu + ((u >> 16) & 1u)) >> 16);
}
__device__ __forceinline__ float bf16tof(u16 h) {
    return __uint_as_float(((u32)h) << 16);
}
__device__ __forceinline__ void split2(float f, u16& h, u16& l) {
    h = bf16rne(f);
    l = bf16rne(f - bf16tof(h));
}

// async global->LDS, 16B/lane; LDS dest wave-uniform base, global src per-lane.
__device__ __forceinline__ void gload16(const void* g, void* l) {
    __builtin_amdgcn_global_load_lds(
        (const __attribute__((address_space(1))) void*)g,
        (__attribute__((address_space(3))) void*)l,
        16, 0, 0);
}

// ---------------- LayerNorm (f32 out) ----------------
__global__ __launch_bounds__(256) void ln_k(const float* __restrict__ in,
                                            const float* __restrict__ gam,
                                            const float* __restrict__ bet,
                                            float* __restrict__ out)
{
    const int row  = blockIdx.x * 4 + (threadIdx.x >> 6);
    const int lane = threadIdx.x & 63;
    const float* p = in + (size_t)row * DIMM + lane * 8;

    float a[8];
    *(float4*)&a[0] = *(const float4*)p;
    *(float4*)&a[4] = *(const float4*)(p + 4);

    float s = 0.f;
    #pragma unroll
    for (int i = 0; i < 8; ++i) s += a[i];
    s = wred_sum(s);
    const float mean = s * (1.0f / DIMM);

    float vs = 0.f;
    #pragma unroll
    for (int i = 0; i < 8; ++i) { float d = a[i] - mean; vs += d * d; }
    vs = wred_sum(vs);
    const float var = vs * (1.0f / DIMM) + 1e-5f;
    float r = rsqrtf(var);
    r = r * (1.5f - 0.5f * var * r * r);

    float g[8], b[8];
    *(float4*)&g[0] = *(const float4*)(gam + lane * 8);
    *(float4*)&g[4] = *(const float4*)(gam + lane * 8 + 4);
    *(float4*)&b[0] = *(const float4*)(bet + lane * 8);
    *(float4*)&b[4] = *(const float4*)(bet + lane * 8 + 4);

    float o[8];
    #pragma unroll
    for (int i = 0; i < 8; ++i) o[i] = g[i] * (a[i] - mean) * r + b[i];

    float* q = out + (size_t)row * DIMM + lane * 8;
    *(float4*)q       = *(float4*)&o[0];
    *(float4*)(q + 4) = *(float4*)&o[4];
}

// ---------------- LayerNorm -> split bf16 (hi,lo) ----------------
__global__ __launch_bounds__(256) void ln_split_k(const float* __restrict__ in,
                                                  const float* __restrict__ gam,
                                                  const float* __restrict__ bet,
                                                  u16* __restrict__ oh,
                                                  u16* __restrict__ ol)
{
    const int row  = blockIdx.x * 4 + (threadIdx.x >> 6);
    const int lane = threadIdx.x & 63;
    const float* p = in + (size_t)row * DIMM + lane * 8;

    float a[8];
    *(float4*)&a[0] = *(const float4*)p;
    *(float4*)&a[4] = *(const float4*)(p + 4);

    float s = 0.f;
    #pragma unroll
    for (int i = 0; i < 8; ++i) s += a[i];
    s = wred_sum(s);
    const float mean = s * (1.0f / DIMM);

    float vs = 0.f;
    #pragma unroll
    for (int i = 0; i < 8; ++i) { float d = a[i] - mean; vs += d * d; }
    vs = wred_sum(vs);
    const float var = vs * (1.0f / DIMM) + 1e-5f;
    float r = rsqrtf(var);
    r = r * (1.5f - 0.5f * var * r * r);

    float g[8], b[8];
    *(float4*)&g[0] = *(const float4*)(gam + lane * 8);
    *(float4*)&g[4] = *(const float4*)(gam + lane * 8 + 4);
    *(float4*)&b[0] = *(const float4*)(bet + lane * 8);
    *(float4*)&b[4] = *(const float4*)(bet + lane * 8 + 4);

    u32 ph[4], pl[4];
    #pragma unroll
    for (int i = 0; i < 4; ++i) {
        float o0 = g[2*i]   * (a[2*i]   - mean) * r + b[2*i];
        float o1 = g[2*i+1] * (a[2*i+1] - mean) * r + b[2*i+1];
        u16 h0, l0, h1, l1;
        split2(o0, h0, l0);
        split2(o1, h1, l1);
        ph[i] = (u32)h0 | ((u32)h1 << 16);
        pl[i] = (u32)l0 | ((u32)l1 << 16);
    }
    uint4 vh; vh.x = ph[0]; vh.y = ph[1]; vh.z = ph[2]; vh.w = ph[3];
    uint4 vl; vl.x = pl[0]; vl.y = pl[1]; vl.z = pl[2]; vl.w = pl[3];
    *(uint4*)(oh + (size_t)row * DIMM + lane * 8) = vh;
    *(uint4*)(ol + (size_t)row * DIMM + lane * 8) = vl;
}

// ---------------- weight transpose + split ----------------
__global__ __launch_bounds__(256) void wsplit_k(const float* __restrict__ W,
                                                u16* __restrict__ Th, u16* __restrict__ Tl,
                                                int K, int N)
{
    __shared__ float t[64][65];
    const int k0 = blockIdx.y * 64, n0 = blockIdx.x * 64;
    const int tid = threadIdx.x;
    #pragma unroll
    for (int p = 0; p < 16; ++p) {
        const int idx = p * 256 + tid;
        const int r = idx >> 6, c = idx & 63;
        t[r][c] = W[(size_t)(k0 + r) * N + n0 + c];
    }
    __syncthreads();
    #pragma unroll
    for (int p = 0; p < 16; ++p) {
        const int idx = p * 256 + tid;
        const int r = idx >> 6, c = idx & 63;
        float v = t[c][r];
        u16 h, l; split2(v, h, l);
        Th[(size_t)(n0 + r) * K + k0 + c] = h;
        Tl[(size_t)(n0 + r) * K + k0 + c] = l;
    }
}

// ---------------- split-bf16 MFMA GEMM: depth-2 prefetch, COUNTED vmcnt (T4) --------------
// C = A[M,K] @ B^T[N,K]^T, 3-term: ahi*bhi + ahi*blo + alo*bhi.
// 128x128 tile, BK=32, 4 waves 2x2, 4x4 frags of 16x16x32. XCD-chunk swizzle (T1).
// Counted-vmcnt schedule (never 0 mid-loop). Invariant: at iter t's wait,
// allowed_outstanding = 8*(staged(t) - t - 1), staged(t)=min(t+2,nt):
//   t <= nt-2 : vmcnt(8)   (tile t done; t+1[,t+2] in flight)
//   t == nt-1 : vmcnt(0)   (TAIL FIX R9: nothing staged beyond t; vmcnt(8) with only
//                           8 outstanding would pass WITHOUT waiting -> race on last tile)
// Per iter: wait -> s_barrier -> ds_read -> lgkmcnt(0) -> s_barrier -> STAGE(t+2) -> MFMA.
// Math order bit-identical to R7/R8 -> absmax must stay 0.05175781 (deviation == race).
#define SM_SWISH          0
#define SM_RESHALF_F32    1
#define SM_RESHALF_SPLIT  2
#define SM_Q              3
#define SM_KV             4
#define SM_RESBIAS        5

template<int MODE>
__global__ __launch_bounds__(256, 2) void mgemm_k(
    const u16* __restrict__ Ahi, const u16* __restrict__ Alo,
    const u16* __restrict__ Bhi, const u16* __restrict__ Blo,
    const float* __restrict__ bias, const float* __restrict__ res,
    float* __restrict__ o1, u16* __restrict__ o2, u16* __restrict__ o3,
    u16* __restrict__ o4, int N, int K, int row0)
{
    __shared__ u16 sAh[2][128 * 32], sAl[2][128 * 32], sBh[2][128 * 32], sBl[2][128 * 32];

    const int tid  = threadIdx.x;
    // bijective XCD-chunk swizzle (nwg multiple of 8)
    const int nwg  = gridDim.x * gridDim.y;
    int bid = blockIdx.y * gridDim.x + blockIdx.x;
    bid = (bid & 7) * (nwg >> 3) + (bid >> 3);
    const int bm   = (bid / gridDim.x) * 128;
    const int bn   = (bid % gridDim.x) * 128;

    const int lane = tid & 63;
    const int wid  = tid >> 6;
    const int wr   = (wid >> 1) * 64;
    const int wc   = (wid & 1) * 64;
    const int colL = lane & 15;
    const int rowL = (lane >> 4) * 4;
    const int kL   = (lane >> 4) * 8;
    const int srow = lane >> 2;
    const int skc  = (lane & 3) * 8;

    const f32x4 z4 = {0.f, 0.f, 0.f, 0.f};
    f32x4 acc[4][4];
    #pragma unroll
    for (int i = 0; i < 4; ++i)
        #pragma unroll
        for (int j = 0; j < 4; ++j) acc[i][j] = z4;

    // 8 async loads/wave into buffer `bf` for K-offset k0
    #define STAGE_TILE(bf, k0)                                                    \
        {                                                                         \
            _Pragma("unroll")                                                     \
            for (int ss = 0; ss < 2; ++ss) {                                      \
                const int s = wid * 2 + ss;                                       \
                const int r = s * 16 + srow;                                      \
                const size_t ga = (size_t)(bm + r) * K + (k0) + skc;              \
                const size_t gb = (size_t)(bn + r) * K + (k0) + skc;              \
                gload16(&Ahi[ga], &sAh[bf][s * 512]);                             \
                gload16(&Alo[ga], &sAl[bf][s * 512]);                             \
                gload16(&Bhi[gb], &sBh[bf][s * 512]);                             \
                gload16(&Blo[gb], &sBl[bf][s * 512]);                             \
            }                                                                     \
        }

    const int nt = K >> 5;
    STAGE_TILE(0, 0);
    if (nt > 1) STAGE_TILE(1, 32);

    int cur = 0;
    for (int t = 0; t < nt; ++t) {
        if (t + 1 < nt) {
            asm volatile("s_waitcnt vmcnt(8)" ::: "memory");   // tile-t loads (mine) done
        } else {
            asm volatile("s_waitcnt vmcnt(0)" ::: "memory");   // TAIL: only 8 outstanding
        }
        __builtin_amdgcn_s_barrier();                      // everyone's tile-t loads done
        __builtin_amdgcn_sched_barrier(0);

        short8 ah[4], al[4], bh[4], bl[4];
        #pragma unroll
        for (int f = 0; f < 4; ++f) {
            const int ra = (wr + f * 16 + colL) * 32 + kL;
            ah[f] = *(const short8*)&sAh[cur][ra];
            al[f] = *(const short8*)&sAl[cur][ra];
            const int rb = (wc + f * 16 + colL) * 32 + kL;
            bh[f] = *(const short8*)&sBh[cur][rb];
            bl[f] = *(const short8*)&sBl[cur][rb];
        }
        asm volatile("s_waitcnt lgkmcnt(0)" ::: "memory"); // my reads retired to regs
        __builtin_amdgcn_sched_barrier(0);
        __builtin_amdgcn_s_barrier();                      // all waves' reads retired
        __builtin_amdgcn_sched_barrier(0);

        if (t + 2 < nt) STAGE_TILE(cur, (t + 2) << 5);     // overwrite just-read buffer
        __builtin_amdgcn_sched_barrier(0);                 // pin issue before MFMA cluster

        #pragma unroll
        for (int fm = 0; fm < 4; ++fm)
            #pragma unroll
            for (int fn = 0; fn < 4; ++fn) {
                acc[fm][fn] = __builtin_amdgcn_mfma_f32_16x16x32_bf16(ah[fm], bh[fn], acc[fm][fn], 0, 0, 0);
                acc[fm][fn] = __builtin_amdgcn_mfma_f32_16x16x32_bf16(ah[fm], bl[fn], acc[fm][fn], 0, 0, 0);
                acc[fm][fn] = __builtin_amdgcn_mfma_f32_16x16x32_bf16(al[fm], bh[fn], acc[fm][fn], 0, 0, 0);
            }

        cur ^= 1;
    }
    #undef STAGE_TILE

    float biasc[4];
    #pragma unroll
    for (int fn = 0; fn < 4; ++fn) biasc[fn] = bias[bn + wc + fn * 16 + colL];

    #pragma unroll
    for (int fm = 0; fm < 4; ++fm) {
        #pragma unroll
        for (int fn = 0; fn < 4; ++fn) {
            const int gc = bn + wc + fn * 16 + colL;
            #pragma unroll
            for (int r = 0; r < 4; ++r) {
                const int gr = bm + wr + fm * 16 + rowL + r;
                float o = acc[fm][fn][r] + biasc[fn];
                if (MODE == SM_SWISH) {
                    float s = o / (1.f + expf(-o));
                    u16 h, l; split2(s, h, l);
                    o2[(size_t)gr * N + gc] = h;
                    o3[(size_t)gr * N + gc] = l;
                } else if (MODE == SM_RESHALF_F32) {
                    o1[(size_t)gr * N + gc] = res[(size_t)gr * N + gc] + 0.5f * o;
                } else if (MODE == SM_RESHALF_SPLIT) {
                    float v = res[(size_t)gr * N + gc] + 0.5f * o;
                    u16 h, l; split2(v, h, l);
                    o2[(size_t)gr * N + gc] = h;
                    o3[(size_t)gr * N + gc] = l;
                } else if (MODE == SM_Q) {
                    const int b_ = gr >> 6, i_ = gr & 63, h_ = gc >> 7, d_ = gc & 127;
                    const size_t idx = (((size_t)(b_ * HEADS + h_) * NN + i_) << 7) + d_;
                    u16 h, l; split2(o, h, l);
                    o2[idx] = h; o3[idx] = l;
                } else if (MODE == SM_KV) {
                    const int grow = row0 + gr;
                    const int b_ = grow >> 11, j_ = grow & 2047;
                    if (gc < DIMM) {
                        const int h_ = gc >> 7, d_ = gc & 127;
                        const size_t idx = (((size_t)(b_ * HEADS + h_) * JJ + j_) << 7) + d_;
                        u16 h, l; split2(o, h, l);
                        o2[idx] = h; o3[idx] = l;
                    } else {
                        const int cc2 = gc - DIMM;
                        const int h_ = cc2 >> 7, d_ = cc2 & 127;
                        o4[((size_t)(b_ * HEADS + h_) * DH + d_) * JJ + j_] = bf16rne(o);
                    }
                } else {  // SM_RESBIAS
                    o1[(size_t)gr * N + gc] = res[(size_t)gr * N + gc] + o;
                }
            }
        }
    }
}

// ---------------- dots = scale * Q @ K^T (3-term split MFMA) ----------------
__global__ __launch_bounds__(256, 2) void dmfma_k(
    const u16* __restrict__ Qh, const u16* __restrict__ Ql,
    const u16* __restrict__ Kh, const u16* __restrict__ Kl,
    float* __restrict__ dots)
{
    __shared__ u16 sQh[64 * 32], sQl[64 * 32], sKh[128 * 32], sKl[128 * 32];

    const int tid  = threadIdx.x;
    const int bh   = blockIdx.y;
    const int jt   = blockIdx.x * 128;
    const int lane = tid & 63;
    const int wid  = tid >> 6;
    const int wr   = (wid >> 1) * 32;
    const int wc   = (wid & 1) * 64;
    const int colL = lane & 15;
    const int rowL = (lane >> 4) * 4;
    const int kL   = (lane >> 4) * 8;
    const int srow = lane >> 2;
    const int skc  = (lane & 3) * 8;

    const size_t qbase = (size_t)bh * NN * DH;
    const size_t kbase = (size_t)bh * JJ * DH;

    const f32x4 z4 = {0.f, 0.f, 0.f, 0.f};
    f32x4 acc[2][4];
    #pragma unroll
    for (int i = 0; i < 2; ++i)
        #pragma unroll
        for (int j = 0; j < 4; ++j) acc[i][j] = z4;

    for (int d0 = 0; d0 < DH; d0 += 32) {
        __syncthreads();
        {
            const size_t gq = qbase + (size_t)(wid * 16 + srow) * DH + d0 + skc;
            gload16(&Qh[gq], &sQh[wid * 512]);
            gload16(&Ql[gq], &sQl[wid * 512]);
        }
        #pragma unroll
        for (int ss = 0; ss < 2; ++ss) {
            const int s = wid * 2 + ss;
            const size_t gk = kbase + (size_t)(jt + s * 16 + srow) * DH + d0 + skc;
            gload16(&Kh[gk], &sKh[s * 512]);
            gload16(&Kl[gk], &sKl[s * 512]);
        }
        __syncthreads();

        short8 qh[2], ql[2], kh[4], kl[4];
        #pragma unroll
        for (int f = 0; f < 2; ++f) {
            const int ra = (wr + f * 16 + colL) * 32 + kL;
            qh[f] = *(const short8*)&sQh[ra];
            ql[f] = *(const short8*)&sQl[ra];
        }
        #pragma unroll
        for (int f = 0; f < 4; ++f) {
            const int rb = (wc + f * 16 + colL) * 32 + kL;
            kh[f] = *(const short8*)&sKh[rb];
            kl[f] = *(const short8*)&sKl[rb];
        }
        #pragma unroll
        for (int fm = 0; fm < 2; ++fm)
            #pragma unroll
            for (int fn = 0; fn < 4; ++fn) {
                acc[fm][fn] = __builtin_amdgcn_mfma_f32_16x16x32_bf16(qh[fm], kh[fn], acc[fm][fn], 0, 0, 0);
                acc[fm][fn] = __builtin_amdgcn_mfma_f32_16x16x32_bf16(qh[fm], kl[fn], acc[fm][fn], 0, 0, 0);
                acc[fm][fn] = __builtin_amdgcn_mfma_f32_16x16x32_bf16(ql[fm], kh[fn], acc[fm][fn], 0, 0, 0);
            }
    }

    const float scl = 0.08838834764831845f;
    #pragma unroll
    for (int fm = 0; fm < 2; ++fm)
        #pragma unroll
        for (int fn = 0; fn < 4; ++fn)
            #pragma unroll
            for (int r = 0; r < 4; ++r) {
                const int qi = wr + fm * 16 + rowL + r;
                const int jc = jt + wc + fn * 16 + colL;
                dots[((size_t)bh * NN + qi) * JJ + jc] = acc[fm][fn][r] * scl;
            }
}

// ---------------- top-k + masked softmax; emits P as bf16 IN-PLACE ----------------
__global__ __launch_bounds__(256) void topk_sm_k(float* __restrict__ dots)
{
    const int wid  = threadIdx.x >> 6;
    const int lane = threadIdx.x & 63;
    const int r = blockIdx.x * 4 + wid;
    const int b = r >> 8;
    const int h = (r >> 6) & 3;
    float* row = dots + (size_t)r * JJ;

    float d[32];
    unsigned key[32];
    #pragma unroll
    for (int t = 0; t < 32; ++t) {
        d[t] = row[lane + 64 * t];
        key[t] = fkey(d[t]);
    }

    unsigned cur = 0u;
    for (int bit = 31; bit >= 0; --bit) {
        const unsigned cand = cur | (1u << bit);
        int c = 0;
        #pragma unroll
        for (int t = 0; t < 32; ++t) c += (key[t] >= cand) ? 1 : 0;
        c = wred_sumi(c);
        if (c >= TOPKK) cur = cand;
    }

    const int LB = (h == 0) ? 1 : (h == 1) ? 4 : (h == 2) ? 8 : 1000;
    float m = -FLTMAXF;
    #pragma unroll
    for (int t = 0; t < 32; ++t) {
        const int j = lane + 64 * t;
        int df = (j >> 6) - b; df = (df < 0) ? -df : df;
        const bool keep = (df <= LB) && (key[t] >= cur);
        d[t] = keep ? d[t] : -FLTMAXF;
        m = fmaxf(m, d[t]);
    }
    m = wred_max(m);

    float s = 0.f;
    float e[32];
    #pragma unroll
    for (int t = 0; t < 32; ++t) {
        e[t] = expf(d[t] - m);
        s += e[t];
    }
    s = wred_sum(s);
    const float inv = 1.0f / s;

    u16* prow = (u16*)row;
    #pragma unroll
    for (int t = 0; t < 32; ++t) prow[lane + 64 * t] = bf16rne(e[t] * inv);
}

// ---------------- attn = P @ V^T-layout (bf16 MFMA, 1-term) ----------------
__global__ __launch_bounds__(256, 2) void pvm_k(
    const u16* __restrict__ Pb,     // [bh][i][j], row pitch 2*JJ u16 (in dots buffer)
    const u16* __restrict__ Vt,     // [bh][d][j]
    u16* __restrict__ attnh, u16* __restrict__ attnl)
{
    __shared__ u16 sP[64 * 32], sVt[128 * 32];

    const int tid  = threadIdx.x;
    const int bh   = blockIdx.x;
    const int lane = tid & 63;
    const int wid  = tid >> 6;
    const int wr   = (wid >> 1) * 32;
    const int wc   = (wid & 1) * 64;
    const int colL = lane & 15;
    const int rowL = (lane >> 4) * 4;
    const int kL   = (lane >> 4) * 8;
    const int srow = lane >> 2;
    const int skc  = (lane & 3) * 8;

    const size_t pbase = (size_t)bh * NN * (2 * JJ);
    const size_t vbase = (size_t)bh * DH * JJ;

    const f32x4 z4 = {0.f, 0.f, 0.f, 0.f};
    f32x4 acc[2][4];
    #pragma unroll
    for (int i = 0; i < 2; ++i)
        #pragma unroll
        for (int j = 0; j < 4; ++j) acc[i][j] = z4;

    for (int j0 = 0; j0 < JJ; j0 += 32) {
        __syncthreads();
        {
            const size_t gp = pbase + (size_t)(wid * 16 + srow) * (2 * JJ) + j0 + skc;
            gload16(&Pb[gp], &sP[wid * 512]);
        }
        #pragma unroll
        for (int ss = 0; ss < 2; ++ss) {
            const int s = wid * 2 + ss;
            const size_t gv = vbase + (size_t)(s * 16 + srow) * JJ + j0 + skc;
            gload16(&Vt[gv], &sVt[s * 512]);
        }
        __syncthreads();

        short8 pf[2], vf[4];
        #pragma unroll
        for (int f = 0; f < 2; ++f)
            pf[f] = *(const short8*)&sP[(wr + f * 16 + colL) * 32 + kL];
        #pragma unroll
        for (int f = 0; f < 4; ++f)
            vf[f] = *(const short8*)&sVt[(wc + f * 16 + colL) * 32 + kL];
        #pragma unroll
        for (int fm = 0; fm < 2; ++fm)
            #pragma unroll
            for (int fn = 0; fn < 4; ++fn)
                acc[fm][fn] = __builtin_amdgcn_mfma_f32_16x16x32_bf16(pf[fm], vf[fn], acc[fm][fn], 0, 0, 0);
    }

    const int b = bh >> 2, h = bh & 3;
    #pragma unroll
    for (int fm = 0; fm < 2; ++fm)
        #pragma unroll
        for (int fn = 0; fn < 4; ++fn)
            #pragma unroll
            for (int r = 0; r < 4; ++r) {
                const int i = wr + fm * 16 + rowL + r;
                const int dcol = wc + fn * 16 + colL;
                const size_t idx = (size_t)(b * NN + i) * DIMM + h * DH + dcol;
                u16 hh, ll; split2(acc[fm][fn][r], hh, ll);
                attnh[idx] = hh; attnl[idx] = ll;
            }
}

// ---------------- host ----------------
extern "C" void kernel_launch(void* const* d_in, const int* in_sizes, int n_in,
                              void* d_out, int out_size, void* d_ws, size_t ws_size,
                              hipStream_t stream)
{
    if (ws_size < WS_WORDS_REQ * 4ull) return;   // OOB guard

    const float* x       = (const float*)d_in[0];
    const float* ctx     = (const float*)d_in[1];
    const float* ff1_w1  = (const float*)d_in[2];
    const float* ff1_b1  = (const float*)d_in[3];
    const float* ff1_w2  = (const float*)d_in[4];
    const float* ff1_b2  = (const float*)d_in[5];
    const float* ffkv_w1 = (const float*)d_in[6];
    const float* ffkv_b1 = (const float*)d_in[7];
    const float* ffkv_w2 = (const float*)d_in[8];
    const float* ffkv_b2 = (const float*)d_in[9];
    const float* wq      = (const float*)d_in[10];
    const float* bq      = (const float*)d_in[11];
    const float* wkv     = (const float*)d_in[12];
    const float* bkv     = (const float*)d_in[13];
    const float* wo      = (const float*)d_in[14];
    const float* bo      = (const float*)d_in[15];
    const float* ln1_g   = (const float*)d_in[16];
    const float* ln1_b   = (const float*)d_in[17];
    const float* lnkv_g  = (const float*)d_in[18];
    const float* lnkv_b  = (const float*)d_in[19];
    const float* lna_g   = (const float*)d_in[20];
    const float* lna_b   = (const float*)d_in[21];
    const float* lnf_g   = (const float*)d_in[22];
    const float* lnf_b   = (const float*)d_in[23];

    float* ws = (float*)d_ws;
    // word layout (82,837,504 words = 331.4 MB) -- unchanged from R6
    u16*   Qhs = (u16*)ws;
    u16*   Qls = Qhs + 1048576;
    u16*   Khs = (u16*)(ws + 1048576);
    u16*   Kls = Khs + 33554432;
    u16*   Vt  = (u16*)(ws + 34603008);
    float* x1  = ws + 51380224;
    float* wsp = x1 + 1048576;
    float* R   = wsp + 5242880;

    u16* w1Th  = (u16*)wsp;
    u16* w1Tl  = w1Th  + 1048576;
    u16* w2Th  = w1Tl  + 1048576;
    u16* w2Tl  = w2Th  + 1048576;
    u16* kw1Th = w2Tl  + 1048576;
    u16* kw1Tl = kw1Th + 1048576;
    u16* kw2Th = kw1Tl + 1048576;
    u16* kw2Tl = kw2Th + 1048576;
    u16* wqTh  = kw2Tl + 1048576;
    u16* wqTl  = wqTh  + 262144;
    u16* wkvTh = wqTl  + 262144;
    u16* wkvTl = wkvTh + 524288;
    u16* woTh  = wkvTl + 524288;
    u16* woTl  = woTh  + 262144;

    // R overlays (temporally disjoint):
    u16* lnxh  = (u16*)R;                       // x path
    u16* lnxl  = lnxh  + 1048576;
    u16* hxh   = lnxl  + 1048576;
    u16* hxl   = hxh   + 4194304;
    u16* lnx2h = hxl   + 4194304;
    u16* lnx2l = lnx2h + 1048576;
    u16* lnch  = (u16*)R;                       // context chunks (CH=8192)
    u16* lncl  = lnch  + 4194304;
    u16* hch   = lncl  + 4194304;
    u16* hcl   = hch   + 16777216;
    u16* ctxnh = hcl   + 16777216;
    u16* ctxnl = ctxnh + 4194304;
    float* dots = R;                            // [8192][2048] f32; P bf16 in-place
    float* x2   = R;                            // after P dead
    u16* attnh  = (u16*)ws;                     // over dead Q split
    u16* attnl  = attnh + 1048576;

    // ---- weight transpose+split ----
    wsplit_k<<<dim3(FFD / 64, DIMM / 64), 256, 0, stream>>>(ff1_w1,  w1Th,  w1Tl,  DIMM, FFD);
    wsplit_k<<<dim3(DIMM / 64, FFD / 64), 256, 0, stream>>>(ff1_w2,  w2Th,  w2Tl,  FFD,  DIMM);
    wsplit_k<<<dim3(FFD / 64, DIMM / 64), 256, 0, stream>>>(ffkv_w1, kw1Th, kw1Tl, DIMM, FFD);
    wsplit_k<<<dim3(DIMM / 64, FFD / 64), 256, 0, stream>>>(ffkv_w2, kw2Th, kw2Tl, FFD,  DIMM);
    wsplit_k<<<dim3(DIMM / 64, DIMM / 64), 256, 0, stream>>>(wq,     wqTh,  wqTl,  DIMM, DIMM);
    wsplit_k<<<dim3(1024 / 64, DIMM / 64), 256, 0, stream>>>(wkv,    wkvTh, wkvTl, DIMM, 1024);
    wsplit_k<<<dim3(DIMM / 64, DIMM / 64), 256, 0, stream>>>(wo,     woTh,  woTl,  DIMM, DIMM);

    // ---- x path ----
    ln_split_k<<<RX / 4, 256, 0, stream>>>(x, ln1_g, ln1_b, lnxh, lnxl);
    mgemm_k<SM_SWISH><<<dim3(FFD / 128, RX / 128), 256, 0, stream>>>(
        lnxh, lnxl, w1Th, w1Tl, ff1_b1, nullptr, nullptr, hxh, hxl, nullptr, FFD, DIMM, 0);
    mgemm_k<SM_RESHALF_F32><<<dim3(DIMM / 128, RX / 128), 256, 0, stream>>>(
        hxh, hxl, w2Th, w2Tl, ff1_b2, x, x1, nullptr, nullptr, nullptr, DIMM, FFD, 0);
    ln_split_k<<<RX / 4, 256, 0, stream>>>(x1, lna_g, lna_b, lnx2h, lnx2l);
    mgemm_k<SM_Q><<<dim3(DIMM / 128, RX / 128), 256, 0, stream>>>(
        lnx2h, lnx2l, wqTh, wqTl, bq, nullptr, nullptr, Qhs, Qls, nullptr, DIMM, DIMM, 0);

    // ---- context chunks (CH=8192, NCH=8) ----
    for (int c = 0; c < NCH; ++c) {
        const float* cptr = ctx + (size_t)c * CH * DIMM;
        ln_split_k<<<CH / 4, 256, 0, stream>>>(cptr, lnkv_g, lnkv_b, lnch, lncl);
        mgemm_k<SM_SWISH><<<dim3(FFD / 128, CH / 128), 256, 0, stream>>>(
            lnch, lncl, kw1Th, kw1Tl, ffkv_b1, nullptr, nullptr, hch, hcl, nullptr, FFD, DIMM, 0);
        mgemm_k<SM_RESHALF_SPLIT><<<dim3(DIMM / 128, CH / 128), 256, 0, stream>>>(
            hch, hcl, kw2Th, kw2Tl, ffkv_b2, cptr, nullptr, ctxnh, ctxnl, nullptr, DIMM, FFD, 0);
        mgemm_k<SM_KV><<<dim3(1024 / 128, CH / 128), 256, 0, stream>>>(
            ctxnh, ctxnl, wkvTh, wkvTl, bkv, nullptr, nullptr, Khs, Kls, Vt, 1024, DIMM, c * CH);
    }

    // ---- attention ----
    dmfma_k<<<dim3(JJ / 128, BB * HEADS), 256, 0, stream>>>(Qhs, Qls, Khs, Kls, dots);
    topk_sm_k<<<(BB * HEADS * NN) / 4, 256, 0, stream>>>(dots);
    pvm_k<<<BB * HEADS, 256, 0, stream>>>((const u16*)dots, Vt, attnh, attnl);

    // ---- output projection + residual + final LN ----
    mgemm_k<SM_RESBIAS><<<dim3(DIMM / 128, RX / 128), 256, 0, stream>>>(
        attnh, attnl, woTh, woTl, bo, x1, x2, nullptr, nullptr, nullptr, DIMM, DIMM, 0);
    ln_k<<<RX / 4, 256, 0, stream>>>(x2, lnf_g, lnf_b, (float*)d_out);
}

// Round 12
// 1713.209 us; speedup vs baseline: 1.2352x; 1.1274x over previous
//
#include <hip/hip_runtime.h>
#include <math.h>

// ---------------- problem constants ----------------
#define BB     32
#define NN     64
#define DIMM   512
#define HEADS  4
#define DH     128
#define FFD    2048
#define JJ     2048
#define RX     2048
#define TOPKK  64
#define FLTMAXF 3.402823466e38f

typedef unsigned short u16;
typedef unsigned int   u32;

using f32x4  = __attribute__((ext_vector_type(4))) float;
using short8 = __attribute__((ext_vector_type(8))) short;   // 8 bf16 (4 VGPRs)

__device__ __forceinline__ float wred_sum(float v) {
    #pragma unroll
    for (int m = 1; m < 64; m <<= 1) v += __shfl_xor(v, m, 64);
    return v;
}
__device__ __forceinline__ int wred_sumi(int v) {
    #pragma unroll
    for (int m = 1; m < 64; m <<= 1) v += __shfl_xor(v, m, 64);
    return v;
}
__device__ __forceinline__ float wred_max(float v) {
    #pragma unroll
    for (int m = 1; m < 64; m <<= 1) v = fmaxf(v, __shfl_xor(v, m, 64));
    return v;
}
__device__ __forceinline__ unsigned fkey(float f) {
    unsigned u = __float_as_uint(f);
    return (u & 0x80000000u) ? ~u : (u | 0x80000000u);
}

// bf16 helpers (RNE)
__device__ __forceinline__ u16 bf16rne(float f) {
    u32 u = __float_as_uint(f);
    return (u16)((u + 0x7FFFu + ((u >> 16) & 1u)) >> 16);
}
__device__ __forceinline__ float bf16tof(u16 h) {
    return __uint_as_float(((u32)h) << 16);
}
__device__ __forceinline__ void split2(float f, u16& h, u16& l) {
    h = bf16rne(f);
    l = bf16rne(f - bf16tof(h));
}

// async global->LDS, 16B/lane; LDS dest wave-uniform base, global src per-lane.
__device__ __forceinline__ void gload16(const void* g, void* l) {
    __builtin_amdgcn_global_load_lds(
        (const __attribute__((address_space(1))) void*)g,
        (__attribute__((address_space(3))) void*)l,
        16, 0, 0);
}

// ---------------- LayerNorm (f32 out) ----------------
__global__ __launch_bounds__(256) void ln_k(const float* __restrict__ in,
                                            const float* __restrict__ gam,
                                            const float* __restrict__ bet,
                                            float* __restrict__ out)
{
    const int row  = blockIdx.x * 4 + (threadIdx.x >> 6);
    const int lane = threadIdx.x & 63;
    const float* p = in + (size_t)row * DIMM + lane * 8;

    float a[8];
    *(float4*)&a[0] = *(const float4*)p;
    *(float4*)&a[4] = *(const float4*)(p + 4);

    float s = 0.f;
    #pragma unroll
    for (int i = 0; i < 8; ++i) s += a[i];
    s = wred_sum(s);
    const float mean = s * (1.0f / DIMM);

    float vs = 0.f;
    #pragma unroll
    for (int i = 0; i < 8; ++i) { float d = a[i] - mean; vs += d * d; }
    vs = wred_sum(vs);
    const float var = vs * (1.0f / DIMM) + 1e-5f;
    float r = rsqrtf(var);
    r = r * (1.5f - 0.5f * var * r * r);

    float g[8], b[8];
    *(float4*)&g[0] = *(const float4*)(gam + lane * 8);
    *(float4*)&g[4] = *(const float4*)(gam + lane * 8 + 4);
    *(float4*)&b[0] = *(const float4*)(bet + lane * 8);
    *(float4*)&b[4] = *(const float4*)(bet + lane * 8 + 4);

    float o[8];
    #pragma unroll
    for (int i = 0; i < 8; ++i) o[i] = g[i] * (a[i] - mean) * r + b[i];

    float* q = out + (size_t)row * DIMM + lane * 8;
    *(float4*)q       = *(float4*)&o[0];
    *(float4*)(q + 4) = *(float4*)&o[4];
}

// ---------------- LayerNorm -> split bf16 (hi,lo) ----------------
__global__ __launch_bounds__(256) void ln_split_k(const float* __restrict__ in,
                                                  const float* __restrict__ gam,
                                                  const float* __restrict__ bet,
                                                  u16* __restrict__ oh,
                                                  u16* __restrict__ ol)
{
    const int row  = blockIdx.x * 4 + (threadIdx.x >> 6);
    const int lane = threadIdx.x & 63;
    const float* p = in + (size_t)row * DIMM + lane * 8;

    float a[8];
    *(float4*)&a[0] = *(const float4*)p;
    *(float4*)&a[4] = *(const float4*)(p + 4);

    float s = 0.f;
    #pragma unroll
    for (int i = 0; i < 8; ++i) s += a[i];
    s = wred_sum(s);
    const float mean = s * (1.0f / DIMM);

    float vs = 0.f;
    #pragma unroll
    for (int i = 0; i < 8; ++i) { float d = a[i] - mean; vs += d * d; }
    vs = wred_sum(vs);
    const float var = vs * (1.0f / DIMM) + 1e-5f;
    float r = rsqrtf(var);
    r = r * (1.5f - 0.5f * var * r * r);

    float g[8], b[8];
    *(float4*)&g[0] = *(const float4*)(gam + lane * 8);
    *(float4*)&g[4] = *(const float4*)(gam + lane * 8 + 4);
    *(float4*)&b[0] = *(const float4*)(bet + lane * 8);
    *(float4*)&b[4] = *(const float4*)(bet + lane * 8 + 4);

    u32 ph[4], pl[4];
    #pragma unroll
    for (int i = 0; i < 4; ++i) {
        float o0 = g[2*i]   * (a[2*i]   - mean) * r + b[2*i];
        float o1 = g[2*i+1] * (a[2*i+1] - mean) * r + b[2*i+1];
        u16 h0, l0, h1, l1;
        split2(o0, h0, l0);
        split2(o1, h1, l1);
        ph[i] = (u32)h0 | ((u32)h1 << 16);
        pl[i] = (u32)l0 | ((u32)l1 << 16);
    }
    uint4 vh; vh.x = ph[0]; vh.y = ph[1]; vh.z = ph[2]; vh.w = ph[3];
    uint4 vl; vl.x = pl[0]; vl.y = pl[1]; vl.z = pl[2]; vl.w = pl[3];
    *(uint4*)(oh + (size_t)row * DIMM + lane * 8) = vh;
    *(uint4*)(ol + (size_t)row * DIMM + lane * 8) = vl;
}

// ---------------- weight transpose + split ----------------
__global__ __launch_bounds__(256) void wsplit_k(const float* __restrict__ W,
                                                u16* __restrict__ Th, u16* __restrict__ Tl,
                                                int K, int N)
{
    __shared__ float t[64][65];
    const int k0 = blockIdx.y * 64, n0 = blockIdx.x * 64;
    const int tid = threadIdx.x;
    #pragma unroll
    for (int p = 0; p < 16; ++p) {
        const int idx = p * 256 + tid;
        const int r = idx >> 6, c = idx & 63;
        t[r][c] = W[(size_t)(k0 + r) * N + n0 + c];
    }
    __syncthreads();
    #pragma unroll
    for (int p = 0; p < 16; ++p) {
        const int idx = p * 256 + tid;
        const int r = idx >> 6, c = idx & 63;
        float v = t[c][r];
        u16 h, l; split2(v, h, l);
        Th[(size_t)(n0 + r) * K + k0 + c] = h;
        Tl[(size_t)(n0 + r) * K + k0 + c] = l;
    }
}

// ---------------- split-bf16 MFMA GEMM: depth-2 prefetch, COUNTED vmcnt (T4) --------------
// UNCHANGED from R9/R10 (validated: absmax bit-stable, +9%).
#define SM_SWISH          0
#define SM_RESHALF_F32    1
#define SM_RESHALF_SPLIT  2
#define SM_Q              3
#define SM_KV             4
#define SM_RESBIAS        5

template<int MODE>
__global__ __launch_bounds__(256, 2) void mgemm_k(
    const u16* __restrict__ Ahi, const u16* __restrict__ Alo,
    const u16* __restrict__ Bhi, const u16* __restrict__ Blo,
    const float* __restrict__ bias, const float* __restrict__ res,
    float* __restrict__ o1, u16* __restrict__ o2, u16* __restrict__ o3,
    u16* __restrict__ o4, int N, int K, int row0)
{
    __shared__ u16 sAh[2][128 * 32], sAl[2][128 * 32], sBh[2][128 * 32], sBl[2][128 * 32];

    const int tid  = threadIdx.x;
    // bijective XCD-chunk swizzle (nwg multiple of 8)
    const int nwg  = gridDim.x * gridDim.y;
    int bid = blockIdx.y * gridDim.x + blockIdx.x;
    bid = (bid & 7) * (nwg >> 3) + (bid >> 3);
    const int bm   = (bid / gridDim.x) * 128;
    const int bn   = (bid % gridDim.x) * 128;

    const int lane = tid & 63;
    const int wid  = tid >> 6;
    const int wr   = (wid >> 1) * 64;
    const int wc   = (wid & 1) * 64;
    const int colL = lane & 15;
    const int rowL = (lane >> 4) * 4;
    const int kL   = (lane >> 4) * 8;
    const int srow = lane >> 2;
    const int skc  = (lane & 3) * 8;

    const f32x4 z4 = {0.f, 0.f, 0.f, 0.f};
    f32x4 acc[4][4];
    #pragma unroll
    for (int i = 0; i < 4; ++i)
        #pragma unroll
        for (int j = 0; j < 4; ++j) acc[i][j] = z4;

    // 8 async loads/wave into buffer `bf` for K-offset k0
    #define STAGE_TILE(bf, k0)                                                    \
        {                                                                         \
            _Pragma("unroll")                                                     \
            for (int ss = 0; ss < 2; ++ss) {                                      \
                const int s = wid * 2 + ss;                                       \
                const int r = s * 16 + srow;                                      \
                const size_t ga = (size_t)(bm + r) * K + (k0) + skc;              \
                const size_t gb = (size_t)(bn + r) * K + (k0) + skc;              \
                gload16(&Ahi[ga], &sAh[bf][s * 512]);                             \
                gload16(&Alo[ga], &sAl[bf][s * 512]);                             \
                gload16(&Bhi[gb], &sBh[bf][s * 512]);                             \
                gload16(&Blo[gb], &sBl[bf][s * 512]);                             \
            }                                                                     \
        }

    const int nt = K >> 5;
    STAGE_TILE(0, 0);
    if (nt > 1) STAGE_TILE(1, 32);

    int cur = 0;
    for (int t = 0; t < nt; ++t) {
        if (t + 1 < nt) {
            asm volatile("s_waitcnt vmcnt(8)" ::: "memory");   // tile-t loads (mine) done
        } else {
            asm volatile("s_waitcnt vmcnt(0)" ::: "memory");   // TAIL: only 8 outstanding
        }
        __builtin_amdgcn_s_barrier();                      // everyone's tile-t loads done
        __builtin_amdgcn_sched_barrier(0);

        short8 ah[4], al[4], bh[4], bl[4];
        #pragma unroll
        for (int f = 0; f < 4; ++f) {
            const int ra = (wr + f * 16 + colL) * 32 + kL;
            ah[f] = *(const short8*)&sAh[cur][ra];
            al[f] = *(const short8*)&sAl[cur][ra];
            const int rb = (wc + f * 16 + colL) * 32 + kL;
            bh[f] = *(const short8*)&sBh[cur][rb];
            bl[f] = *(const short8*)&sBl[cur][rb];
        }
        asm volatile("s_waitcnt lgkmcnt(0)" ::: "memory"); // my reads retired to regs
        __builtin_amdgcn_sched_barrier(0);
        __builtin_amdgcn_s_barrier();                      // all waves' reads retired
        __builtin_amdgcn_sched_barrier(0);

        if (t + 2 < nt) STAGE_TILE(cur, (t + 2) << 5);     // overwrite just-read buffer
        __builtin_amdgcn_sched_barrier(0);                 // pin issue before MFMA cluster

        #pragma unroll
        for (int fm = 0; fm < 4; ++fm)
            #pragma unroll
            for (int fn = 0; fn < 4; ++fn) {
                acc[fm][fn] = __builtin_amdgcn_mfma_f32_16x16x32_bf16(ah[fm], bh[fn], acc[fm][fn], 0, 0, 0);
                acc[fm][fn] = __builtin_amdgcn_mfma_f32_16x16x32_bf16(ah[fm], bl[fn], acc[fm][fn], 0, 0, 0);
                acc[fm][fn] = __builtin_amdgcn_mfma_f32_16x16x32_bf16(al[fm], bh[fn], acc[fm][fn], 0, 0, 0);
            }

        cur ^= 1;
    }
    #undef STAGE_TILE

    float biasc[4];
    #pragma unroll
    for (int fn = 0; fn < 4; ++fn) biasc[fn] = bias[bn + wc + fn * 16 + colL];

    #pragma unroll
    for (int fm = 0; fm < 4; ++fm) {
        #pragma unroll
        for (int fn = 0; fn < 4; ++fn) {
            const int gc = bn + wc + fn * 16 + colL;
            #pragma unroll
            for (int r = 0; r < 4; ++r) {
                const int gr = bm + wr + fm * 16 + rowL + r;
                float o = acc[fm][fn][r] + biasc[fn];
                if (MODE == SM_SWISH) {
                    float s = o / (1.f + expf(-o));
                    u16 h, l; split2(s, h, l);
                    o2[(size_t)gr * N + gc] = h;
                    o3[(size_t)gr * N + gc] = l;
                } else if (MODE == SM_RESHALF_F32) {
                    o1[(size_t)gr * N + gc] = res[(size_t)gr * N + gc] + 0.5f * o;
                } else if (MODE == SM_RESHALF_SPLIT) {
                    float v = res[(size_t)gr * N + gc] + 0.5f * o;
                    u16 h, l; split2(v, h, l);
                    o2[(size_t)gr * N + gc] = h;
                    o3[(size_t)gr * N + gc] = l;
                } else if (MODE == SM_Q) {
                    const int b_ = gr >> 6, i_ = gr & 63, h_ = gc >> 7, d_ = gc & 127;
                    const size_t idx = (((size_t)(b_ * HEADS + h_) * NN + i_) << 7) + d_;
                    u16 h, l; split2(o, h, l);
                    o2[idx] = h; o3[idx] = l;
                } else if (MODE == SM_KV) {
                    const int grow = row0 + gr;
                    const int b_ = grow >> 11, j_ = grow & 2047;
                    if (gc < DIMM) {
                        const int h_ = gc >> 7, d_ = gc & 127;
                        const size_t idx = (((size_t)(b_ * HEADS + h_) * JJ + j_) << 7) + d_;
                        u16 h, l; split2(o, h, l);
                        o2[idx] = h; o3[idx] = l;
                    } else {
                        const int cc2 = gc - DIMM;
                        const int h_ = cc2 >> 7, d_ = cc2 & 127;
                        o4[((size_t)(b_ * HEADS + h_) * DH + d_) * JJ + j_] = bf16rne(o);
                    }
                } else {  // SM_RESBIAS
                    o1[(size_t)gr * N + gc] = res[(size_t)gr * N + gc] + o;
                }
            }
        }
    }
}

// ---------------- dots = scale * Q @ K^T (3-term split MFMA) ----------------
__global__ __launch_bounds__(256, 2) void dmfma_k(
    const u16* __restrict__ Qh, const u16* __restrict__ Ql,
    const u16* __restrict__ Kh, const u16* __restrict__ Kl,
    float* __restrict__ dots)
{
    __shared__ u16 sQh[64 * 32], sQl[64 * 32], sKh[128 * 32], sKl[128 * 32];

    const int tid  = threadIdx.x;
    const int bh   = blockIdx.y;
    const int jt   = blockIdx.x * 128;
    const int lane = tid & 63;
    const int wid  = tid >> 6;
    const int wr   = (wid >> 1) * 32;
    const int wc   = (wid & 1) * 64;
    const int colL = lane & 15;
    const int rowL = (lane >> 4) * 4;
    const int kL   = (lane >> 4) * 8;
    const int srow = lane >> 2;
    const int skc  = (lane & 3) * 8;

    const size_t qbase = (size_t)bh * NN * DH;
    const size_t kbase = (size_t)bh * JJ * DH;

    const f32x4 z4 = {0.f, 0.f, 0.f, 0.f};
    f32x4 acc[2][4];
    #pragma unroll
    for (int i = 0; i < 2; ++i)
        #pragma unroll
        for (int j = 0; j < 4; ++j) acc[i][j] = z4;

    for (int d0 = 0; d0 < DH; d0 += 32) {
        __syncthreads();
        {
            const size_t gq = qbase + (size_t)(wid * 16 + srow) * DH + d0 + skc;
            gload16(&Qh[gq], &sQh[wid * 512]);
            gload16(&Ql[gq], &sQl[wid * 512]);
        }
        #pragma unroll
        for (int ss = 0; ss < 2; ++ss) {
            const int s = wid * 2 + ss;
            const size_t gk = kbase + (size_t)(jt + s * 16 + srow) * DH + d0 + skc;
            gload16(&Kh[gk], &sKh[s * 512]);
            gload16(&Kl[gk], &sKl[s * 512]);
        }
        __syncthreads();

        short8 qh[2], ql[2], kh[4], kl[4];
        #pragma unroll
        for (int f = 0; f < 2; ++f) {
            const int ra = (wr + f * 16 + colL) * 32 + kL;
            qh[f] = *(const short8*)&sQh[ra];
            ql[f] = *(const short8*)&sQl[ra];
        }
        #pragma unroll
        for (int f = 0; f < 4; ++f) {
            const int rb = (wc + f * 16 + colL) * 32 + kL;
            kh[f] = *(const short8*)&sKh[rb];
            kl[f] = *(const short8*)&sKl[rb];
        }
        #pragma unroll
        for (int fm = 0; fm < 2; ++fm)
            #pragma unroll
            for (int fn = 0; fn < 4; ++fn) {
                acc[fm][fn] = __builtin_amdgcn_mfma_f32_16x16x32_bf16(qh[fm], kh[fn], acc[fm][fn], 0, 0, 0);
                acc[fm][fn] = __builtin_amdgcn_mfma_f32_16x16x32_bf16(qh[fm], kl[fn], acc[fm][fn], 0, 0, 0);
                acc[fm][fn] = __builtin_amdgcn_mfma_f32_16x16x32_bf16(ql[fm], kh[fn], acc[fm][fn], 0, 0, 0);
            }
    }

    const float scl = 0.08838834764831845f;
    #pragma unroll
    for (int fm = 0; fm < 2; ++fm)
        #pragma unroll
        for (int fn = 0; fn < 4; ++fn)
            #pragma unroll
            for (int r = 0; r < 4; ++r) {
                const int qi = wr + fm * 16 + rowL + r;
                const int jc = jt + wc + fn * 16 + colL;
                dots[((size_t)bh * NN + qi) * JJ + jc] = acc[fm][fn][r] * scl;
            }
}

// ---------------- top-k + masked softmax; emits P as bf16 IN-PLACE ----------------
__global__ __launch_bounds__(256) void topk_sm_k(float* __restrict__ dots)
{
    const int wid  = threadIdx.x >> 6;
    const int lane = threadIdx.x & 63;
    const int r = blockIdx.x * 4 + wid;
    const int b = r >> 8;
    const int h = (r >> 6) & 3;
    float* row = dots + (size_t)r * JJ;

    float d[32];
    unsigned key[32];
    #pragma unroll
    for (int t = 0; t < 32; ++t) {
        d[t] = row[lane + 64 * t];
        key[t] = fkey(d[t]);
    }

    unsigned cur = 0u;
    for (int bit = 31; bit >= 0; --bit) {
        const unsigned cand = cur | (1u << bit);
        int c = 0;
        #pragma unroll
        for (int t = 0; t < 32; ++t) c += (key[t] >= cand) ? 1 : 0;
        c = wred_sumi(c);
        if (c >= TOPKK) cur = cand;
    }

    const int LB = (h == 0) ? 1 : (h == 1) ? 4 : (h == 2) ? 8 : 1000;
    float m = -FLTMAXF;
    #pragma unroll
    for (int t = 0; t < 32; ++t) {
        const int j = lane + 64 * t;
        int df = (j >> 6) - b; df = (df < 0) ? -df : df;
        const bool keep = (df <= LB) && (key[t] >= cur);
        d[t] = keep ? d[t] : -FLTMAXF;
        m = fmaxf(m, d[t]);
    }
    m = wred_max(m);

    float s = 0.f;
    float e[32];
    #pragma unroll
    for (int t = 0; t < 32; ++t) {
        e[t] = expf(d[t] - m);
        s += e[t];
    }
    s = wred_sum(s);
    const float inv = 1.0f / s;

    u16* prow = (u16*)row;
    #pragma unroll
    for (int t = 0; t < 32; ++t) prow[lane + 64 * t] = bf16rne(e[t] * inv);
}

// ---------------- attn = P @ V^T-layout (bf16 MFMA, 1-term) ----------------
__global__ __launch_bounds__(256, 2) void pvm_k(
    const u16* __restrict__ Pb,     // [bh][i][j], row pitch 2*JJ u16 (in dots buffer)
    const u16* __restrict__ Vt,     // [bh][d][j]
    u16* __restrict__ attnh, u16* __restrict__ attnl)
{
    __shared__ u16 sP[64 * 32], sVt[128 * 32];

    const int tid  = threadIdx.x;
    const int bh   = blockIdx.x;
    const int lane = tid & 63;
    const int wid  = tid >> 6;
    const int wr   = (wid >> 1) * 32;
    const int wc   = (wid & 1) * 64;
    const int colL = lane & 15;
    const int rowL = (lane >> 4) * 4;
    const int kL   = (lane >> 4) * 8;
    const int srow = lane >> 2;
    const int skc  = (lane & 3) * 8;

    const size_t pbase = (size_t)bh * NN * (2 * JJ);
    const size_t vbase = (size_t)bh * DH * JJ;

    const f32x4 z4 = {0.f, 0.f, 0.f, 0.f};
    f32x4 acc[2][4];
    #pragma unroll
    for (int i = 0; i < 2; ++i)
        #pragma unroll
        for (int j = 0; j < 4; ++j) acc[i][j] = z4;

    for (int j0 = 0; j0 < JJ; j0 += 32) {
        __syncthreads();
        {
            const size_t gp = pbase + (size_t)(wid * 16 + srow) * (2 * JJ) + j0 + skc;
            gload16(&Pb[gp], &sP[wid * 512]);
        }
        #pragma unroll
        for (int ss = 0; ss < 2; ++ss) {
            const int s = wid * 2 + ss;
            const size_t gv = vbase + (size_t)(s * 16 + srow) * JJ + j0 + skc;
            gload16(&Vt[gv], &sVt[s * 512]);
        }
        __syncthreads();

        short8 pf[2], vf[4];
        #pragma unroll
        for (int f = 0; f < 2; ++f)
            pf[f] = *(const short8*)&sP[(wr + f * 16 + colL) * 32 + kL];
        #pragma unroll
        for (int f = 0; f < 4; ++f)
            vf[f] = *(const short8*)&sVt[(wc + f * 16 + colL) * 32 + kL];
        #pragma unroll
        for (int fm = 0; fm < 2; ++fm)
            #pragma unroll
            for (int fn = 0; fn < 4; ++fn)
                acc[fm][fn] = __builtin_amdgcn_mfma_f32_16x16x32_bf16(pf[fm], vf[fn], acc[fm][fn], 0, 0, 0);
    }

    const int b = bh >> 2, h = bh & 3;
    #pragma unroll
    for (int fm = 0; fm < 2; ++fm)
        #pragma unroll
        for (int fn = 0; fn < 4; ++fn)
            #pragma unroll
            for (int r = 0; r < 4; ++r) {
                const int i = wr + fm * 16 + rowL + r;
                const int dcol = wc + fn * 16 + colL;
                const size_t idx = (size_t)(b * NN + i) * DIMM + h * DH + dcol;
                u16 hh, ll; split2(acc[fm][fn][r], hh, ll);
                attnh[idx] = hh; attnl[idx] = ll;
            }
}

// ---------------- host ----------------
extern "C" void kernel_launch(void* const* d_in, const int* in_sizes, int n_in,
                              void* d_out, int out_size, void* d_ws, size_t ws_size,
                              hipStream_t stream)
{
    // Runtime chunk-size selection (audited R12): chunk scratch = ch*3072 words in R.
    // ch=16384 doubles the N=512 GEMM grids (256->512 blocks = 2 resident blocks/CU).
    // Fill-kernel evidence (R10 rocprof): ws_size = 512 MiB -> 16384 fits (432 MB).
    // Fallback to the R6-proven ch=8192 (331.4 MB) if ws is smaller; guard below that.
    const unsigned long long fixed_words = 57671680ull;            // layout through R
    const unsigned long long words8  = fixed_words +  8192ull * 3072ull;  //  82,837,504
    const unsigned long long words16 = fixed_words + 16384ull * 3072ull;  // 108,003,328
    if (ws_size < words8 * 4ull) return;                            // OOB guard
    const int ch  = (ws_size >= words16 * 4ull) ? 16384 : 8192;
    const int nch = 65536 / ch;

    const float* x       = (const float*)d_in[0];
    const float* ctx     = (const float*)d_in[1];
    const float* ff1_w1  = (const float*)d_in[2];
    const float* ff1_b1  = (const float*)d_in[3];
    const float* ff1_w2  = (const float*)d_in[4];
    const float* ff1_b2  = (const float*)d_in[5];
    const float* ffkv_w1 = (const float*)d_in[6];
    const float* ffkv_b1 = (const float*)d_in[7];
    const float* ffkv_w2 = (const float*)d_in[8];
    const float* ffkv_b2 = (const float*)d_in[9];
    const float* wq      = (const float*)d_in[10];
    const float* bq      = (const float*)d_in[11];
    const float* wkv     = (const float*)d_in[12];
    const float* bkv     = (const float*)d_in[13];
    const float* wo      = (const float*)d_in[14];
    const float* bo      = (const float*)d_in[15];
    const float* ln1_g   = (const float*)d_in[16];
    const float* ln1_b   = (const float*)d_in[17];
    const float* lnkv_g  = (const float*)d_in[18];
    const float* lnkv_b  = (const float*)d_in[19];
    const float* lna_g   = (const float*)d_in[20];
    const float* lna_b   = (const float*)d_in[21];
    const float* lnf_g   = (const float*)d_in[22];
    const float* lnf_b   = (const float*)d_in[23];

    float* ws = (float*)d_ws;
    // fixed word layout (matches fixed_words):
    u16*   Qhs = (u16*)ws;
    u16*   Qls = Qhs + 1048576;
    u16*   Khs = (u16*)(ws + 1048576);
    u16*   Kls = Khs + 33554432;
    u16*   Vt  = (u16*)(ws + 34603008);
    float* x1  = ws + 51380224;
    float* wsp = x1 + 1048576;
    float* R   = wsp + 5242880;                 // union region starts at word 57,671,680

    u16* w1Th  = (u16*)wsp;
    u16* w1Tl  = w1Th  + 1048576;
    u16* w2Th  = w1Tl  + 1048576;
    u16* w2Tl  = w2Th  + 1048576;
    u16* kw1Th = w2Tl  + 1048576;
    u16* kw1Tl = kw1Th + 1048576;
    u16* kw2Th = kw1Tl + 1048576;
    u16* kw2Tl = kw2Th + 1048576;
    u16* wqTh  = kw2Tl + 1048576;
    u16* wqTl  = wqTh  + 262144;
    u16* wkvTh = wqTl  + 262144;
    u16* wkvTl = wkvTh + 524288;
    u16* woTh  = wkvTl + 524288;
    u16* woTl  = woTh  + 262144;

    // R overlays (temporally disjoint):
    u16* lnxh  = (u16*)R;                       // x path
    u16* lnxl  = lnxh  + 1048576;
    u16* hxh   = lnxl  + 1048576;
    u16* hxl   = hxh   + 4194304;
    u16* lnx2h = hxl   + 4194304;
    u16* lnx2l = lnx2h + 1048576;
    // context chunks (runtime ch):
    u16* lnch  = (u16*)R;                       // [ch][512]
    u16* lncl  = lnch  + (size_t)ch * 512;
    u16* hch   = lncl  + (size_t)ch * 512;      // [ch][2048]
    u16* hcl   = hch   + (size_t)ch * 2048;
    u16* ctxnh = hcl   + (size_t)ch * 2048;     // [ch][512]
    u16* ctxnl = ctxnh + (size_t)ch * 512;
    float* dots = R;                            // [8192][2048] f32; P bf16 in-place
    float* x2   = R;                            // after P dead
    u16* attnh  = (u16*)ws;                     // over dead Q split
    u16* attnl  = attnh + 1048576;

    // ---- weight transpose+split ----
    wsplit_k<<<dim3(FFD / 64, DIMM / 64), 256, 0, stream>>>(ff1_w1,  w1Th,  w1Tl,  DIMM, FFD);
    wsplit_k<<<dim3(DIMM / 64, FFD / 64), 256, 0, stream>>>(ff1_w2,  w2Th,  w2Tl,  FFD,  DIMM);
    wsplit_k<<<dim3(FFD / 64, DIMM / 64), 256, 0, stream>>>(ffkv_w1, kw1Th, kw1Tl, DIMM, FFD);
    wsplit_k<<<dim3(DIMM / 64, FFD / 64), 256, 0, stream>>>(ffkv_w2, kw2Th, kw2Tl, FFD,  DIMM);
    wsplit_k<<<dim3(DIMM / 64, DIMM / 64), 256, 0, stream>>>(wq,     wqTh,  wqTl,  DIMM, DIMM);
    wsplit_k<<<dim3(1024 / 64, DIMM / 64), 256, 0, stream>>>(wkv,    wkvTh, wkvTl, DIMM, 1024);
    wsplit_k<<<dim3(DIMM / 64, DIMM / 64), 256, 0, stream>>>(wo,     woTh,  woTl,  DIMM, DIMM);

    // ---- x path ----
    ln_split_k<<<RX / 4, 256, 0, stream>>>(x, ln1_g, ln1_b, lnxh, lnxl);
    mgemm_k<SM_SWISH><<<dim3(FFD / 128, RX / 128), 256, 0, stream>>>(
        lnxh, lnxl, w1Th, w1Tl, ff1_b1, nullptr, nullptr, hxh, hxl, nullptr, FFD, DIMM, 0);
    mgemm_k<SM_RESHALF_F32><<<dim3(DIMM / 128, RX / 128), 256, 0, stream>>>(
        hxh, hxl, w2Th, w2Tl, ff1_b2, x, x1, nullptr, nullptr, nullptr, DIMM, FFD, 0);
    ln_split_k<<<RX / 4, 256, 0, stream>>>(x1, lna_g, lna_b, lnx2h, lnx2l);
    mgemm_k<SM_Q><<<dim3(DIMM / 128, RX / 128), 256, 0, stream>>>(
        lnx2h, lnx2l, wqTh, wqTl, bq, nullptr, nullptr, Qhs, Qls, nullptr, DIMM, DIMM, 0);

    // ---- context chunks (runtime ch, nch) ----
    for (int c = 0; c < nch; ++c) {
        const float* cptr = ctx + (size_t)c * ch * DIMM;
        ln_split_k<<<ch / 4, 256, 0, stream>>>(cptr, lnkv_g, lnkv_b, lnch, lncl);
        mgemm_k<SM_SWISH><<<dim3(FFD / 128, ch / 128), 256, 0, stream>>>(
            lnch, lncl, kw1Th, kw1Tl, ffkv_b1, nullptr, nullptr, hch, hcl, nullptr, FFD, DIMM, 0);
        mgemm_k<SM_RESHALF_SPLIT><<<dim3(DIMM / 128, ch / 128), 256, 0, stream>>>(
            hch, hcl, kw2Th, kw2Tl, ffkv_b2, cptr, nullptr, ctxnh, ctxnl, nullptr, DIMM, FFD, 0);
        mgemm_k<SM_KV><<<dim3(1024 / 128, ch / 128), 256, 0, stream>>>(
            ctxnh, ctxnl, wkvTh, wkvTl, bkv, nullptr, nullptr, Khs, Kls, Vt, 1024, DIMM, c * ch);
    }

    // ---- attention ----
    dmfma_k<<<dim3(JJ / 128, BB * HEADS), 256, 0, stream>>>(Qhs, Qls, Khs, Kls, dots);
    topk_sm_k<<<(BB * HEADS * NN) / 4, 256, 0, stream>>>(dots);
    pvm_k<<<BB * HEADS, 256, 0, stream>>>((const u16*)dots, Vt, attnh, attnl);

    // ---- output projection + residual + final LN ----
    mgemm_k<SM_RESBIAS><<<dim3(DIMM / 128, RX / 128), 256, 0, stream>>>(
        attnh, attnl, woTh, woTl, bo, x1, x2, nullptr, nullptr, nullptr, DIMM, DIMM, 0);
    ln_k<<<RX / 4, 256, 0, stream>>>(x2, lnf_g, lnf_b, (float*)d_out);
}